// Round 1
// baseline (11304.650 us; speedup 1.0000x reference)
//
#include <hip/hip_runtime.h>
#include <hip/hip_fp16.h>
#include <hip/hip_cooperative_groups.h>

namespace cg = cooperative_groups;

typedef _Float16 f16;
typedef _Float16 half8 __attribute__((ext_vector_type(8)));
typedef _Float16 f16x4 __attribute__((ext_vector_type(4)));
typedef float floatx4 __attribute__((ext_vector_type(4)));

#define BATCH 64
#define SEQ 512
#define EMB 512
#define HID 1024

// ---------------- K0: W_aa fp32 -> f16 copy in ws ----------------
__global__ __launch_bounds__(256) void k0_cvt_waa(const float* __restrict__ W,
                                                  f16* __restrict__ W16) {
    int i = (blockIdx.x * 256 + threadIdx.x) * 4;
    float4 v = *(const float4*)(W + i);
    f16x4 h;
    h[0] = (f16)v.x; h[1] = (f16)v.y; h[2] = (f16)v.z; h[3] = (f16)v.w;
    *(f16x4*)(W16 + i) = h;
}

// ---------------- K1: xproj = X @ W_ax^T + b_a, stored into d_out[s][b][h] ---
// fp16 split-2: X = X_hi + X_lo (both f16), W_ax single f16. 64x64 tile, 4 waves 2x2.
__global__ __launch_bounds__(256) void k1_xproj(const float* __restrict__ X,
                                                const float* __restrict__ Wax,
                                                const float* __restrict__ ba,
                                                float* __restrict__ out) {
    __shared__ __align__(16) f16 Xhi[64][40];  // +8 pad: 2-way max bank alias (free)
    __shared__ __align__(16) f16 Xlo[64][40];
    __shared__ __align__(16) f16 Wh[64][40];
    const int tid  = threadIdx.x;
    const int lane = tid & 63;
    const int wave = tid >> 6;
    const int vm = wave >> 1, vn = wave & 1;
    const int m0 = blockIdx.x * 64;   // m = b*512 + s  (X flat row)
    const int n0 = blockIdx.y * 64;   // n = h
    const int q = lane >> 4, c = lane & 15;
    const int srow = tid >> 2, scol = (tid & 3) * 8;

    floatx4 acc[2][2] = {};

    for (int kc = 0; kc < EMB; kc += 32) {
        // stage X tile (fp32 -> hi/lo f16)
        const float* xp = X + (size_t)(m0 + srow) * EMB + kc + scol;
        float4 x0 = *(const float4*)xp;
        float4 x1 = *(const float4*)(xp + 4);
        float xv[8] = {x0.x, x0.y, x0.z, x0.w, x1.x, x1.y, x1.z, x1.w};
        half8 xh, xl;
#pragma unroll
        for (int j = 0; j < 8; j++) {
            f16 h = (f16)xv[j];
            xh[j] = h;
            xl[j] = (f16)(xv[j] - (float)h);
        }
        *(half8*)&Xhi[srow][scol] = xh;
        *(half8*)&Xlo[srow][scol] = xl;
        // stage W_ax tile (single f16)
        const float* wp = Wax + (size_t)(n0 + srow) * EMB + kc + scol;
        float4 w0 = *(const float4*)wp;
        float4 w1 = *(const float4*)(wp + 4);
        float wv[8] = {w0.x, w0.y, w0.z, w0.w, w1.x, w1.y, w1.z, w1.w};
        half8 wh8;
#pragma unroll
        for (int j = 0; j < 8; j++) wh8[j] = (f16)wv[j];
        *(half8*)&Wh[srow][scol] = wh8;
        __syncthreads();

#pragma unroll
        for (int im = 0; im < 2; im++) {
            half8 ahi = *(const half8*)&Xhi[vm * 32 + im * 16 + c][q * 8];
            half8 alo = *(const half8*)&Xlo[vm * 32 + im * 16 + c][q * 8];
#pragma unroll
            for (int in = 0; in < 2; in++) {
                half8 bf = *(const half8*)&Wh[vn * 32 + in * 16 + c][q * 8];
                acc[im][in] = __builtin_amdgcn_mfma_f32_16x16x32_f16(ahi, bf, acc[im][in], 0, 0, 0);
                acc[im][in] = __builtin_amdgcn_mfma_f32_16x16x32_f16(alo, bf, acc[im][in], 0, 0, 0);
            }
        }
        __syncthreads();
    }
    // epilogue: D lane l, reg r -> m = q*4+r (X row), n = c (h). out[s][b][h].
#pragma unroll
    for (int im = 0; im < 2; im++) {
#pragma unroll
        for (int in = 0; in < 2; in++) {
            int n = n0 + vn * 32 + in * 16 + c;
            float bias = ba[n];
#pragma unroll
            for (int r = 0; r < 4; r++) {
                int m = m0 + vm * 32 + im * 16 + q * 4 + r;
                int b = m >> 9, s = m & 511;
                out[(size_t)(s * BATCH + b) * HID + n] = acc[im][in][r] + bias;
            }
        }
    }
}

// ---------------- K2: cooperative scan ----------------
// 64 WGs x 256 thr. Wave g (0..255): j-tile (g&63)*16, b-tile (g>>6)*16, full K=1024.
// a state double-buffered in ws as f16 hi/lo planes; xproj read+overwritten in d_out.
__global__ __launch_bounds__(256) void k2_scan(const f16* __restrict__ W16,
                                               float* __restrict__ out,
                                               f16* __restrict__ abuf) {
    cg::grid_group grid = cg::this_grid();
    const int tid = threadIdx.x;
    // zero-init buffer 0 (hi+lo = 131072 halfs = 65536 dwords) across 16384 threads
    {
        uint32_t* z = (uint32_t*)abuf;
        int gtid = blockIdx.x * 256 + tid;
#pragma unroll
        for (int i = 0; i < 4; i++) z[gtid + i * 16384] = 0u;
    }
    const int lane = tid & 63;
    const int wave = tid >> 6;
    const int g = blockIdx.x * 4 + wave;
    const int j0 = (g & 63) * 16;
    const int b0 = (g >> 6) * 16;
    const int q = lane >> 4, c = lane & 15;
    const f16* Wrow = W16 + (size_t)(j0 + c) * HID;  // A-frag row = j0 + (lane&15)
    f16* const bhi0 = abuf;
    f16* const blo0 = abuf + 65536;
    f16* const bhi1 = abuf + 131072;
    f16* const blo1 = abuf + 196608;
    grid.sync();

    for (int s = 0; s < SEQ; s++) {
        const f16* ahi = ((s & 1) ? bhi1 : bhi0) + (size_t)(b0 + c) * HID;
        const f16* alo = ((s & 1) ? blo1 : blo0) + (size_t)(b0 + c) * HID;
        f16* nhi = ((s & 1) ? bhi0 : bhi1);
        f16* nlo = ((s & 1) ? blo0 : blo1);
        floatx4 acc = {0.f, 0.f, 0.f, 0.f};
#pragma unroll 4
        for (int kc = 0; kc < HID; kc += 32) {
            half8 wf = *(const half8*)(Wrow + kc + q * 8);
            half8 hf = *(const half8*)(ahi + kc + q * 8);
            half8 lf = *(const half8*)(alo + kc + q * 8);
            acc = __builtin_amdgcn_mfma_f32_16x16x32_f16(wf, hf, acc, 0, 0, 0);
            acc = __builtin_amdgcn_mfma_f32_16x16x32_f16(wf, lf, acc, 0, 0, 0);
        }
        // lane l, reg r: j = j0 + q*4 + r, b = b0 + c
        const int b = b0 + c;
        size_t obase = ((size_t)s * BATCH + b) * HID + j0 + q * 4;
        float4 xp = *(const float4*)(out + obase);
        float4 v;
        v.x = tanhf(xp.x + acc[0]);
        v.y = tanhf(xp.y + acc[1]);
        v.z = tanhf(xp.z + acc[2]);
        v.w = tanhf(xp.w + acc[3]);
        *(float4*)(out + obase) = v;  // overwrite xproj with output (same rows only)
        float vv[4] = {v.x, v.y, v.z, v.w};
        f16x4 hv, lv;
#pragma unroll
        for (int r = 0; r < 4; r++) {
            f16 h = (f16)vv[r];
            hv[r] = h;
            lv[r] = (f16)(vv[r] - (float)h);
        }
        size_t aoff = (size_t)b * HID + j0 + q * 4;
        *(f16x4*)(nhi + aoff) = hv;
        *(f16x4*)(nlo + aoff) = lv;
        if (s == SEQ - 1) {
            *(float4*)(out + (size_t)SEQ * BATCH * HID + aoff) = v;  // hidden
        }
        grid.sync();
    }
}

extern "C" void kernel_launch(void* const* d_in, const int* in_sizes, int n_in,
                              void* d_out, int out_size, void* d_ws, size_t ws_size,
                              hipStream_t stream) {
    const float* X   = (const float*)d_in[0];
    const float* Wax = (const float*)d_in[1];
    const float* Waa = (const float*)d_in[2];
    const float* ba  = (const float*)d_in[3];
    float* out = (float*)d_out;

    // ws: [a dbl-buf hi/lo: 262144 halfs = 512 KB][W_aa f16: 1048576 halfs = 2 MB]
    f16* abuf = (f16*)d_ws;
    f16* W16  = abuf + 262144;

    k0_cvt_waa<<<dim3(HID * HID / 1024), dim3(256), 0, stream>>>(Waa, W16);
    k1_xproj<<<dim3((BATCH * SEQ) / 64, HID / 64), dim3(256), 0, stream>>>(X, Wax, ba, out);

    void* args[] = {(void*)&W16, (void*)&out, (void*)&abuf};
    hipLaunchCooperativeKernel((void*)k2_scan, dim3(64), dim3(256), args, 0, stream);
}

// Round 2
// 6847.434 us; speedup vs baseline: 1.6509x; 1.6509x over previous
//
#include <hip/hip_runtime.h>
#include <hip/hip_fp16.h>
#include <hip/hip_cooperative_groups.h>

typedef _Float16 f16;
typedef _Float16 half8 __attribute__((ext_vector_type(8)));
typedef _Float16 f16x4 __attribute__((ext_vector_type(4)));
typedef float floatx4 __attribute__((ext_vector_type(4)));

#define BATCH 64
#define SEQ 512
#define EMB 512
#define HID 1024
#define GWG 8  // workgroups per b-group (512 threads each -> 64 waves/group)

// ws layout (bytes):
//   [0, 262144)          abuf: 4 groups x 2 parity x 16384 f16 (state, f16 single plane)
//   [262144, 2359296)    W16: W_aa as f16, 1M elements
//   [2359296, +1KB)      barrier counters, 4 x u32 at 256B stride
#define ABUF_HALFS 131072
#define BAR_OFF 2359296

// ---------------- K0: convert W_aa fp32->f16; zero state buf0 + counters -----
__global__ __launch_bounds__(256) void k0_cvt_waa(const float* __restrict__ W,
                                                  f16* __restrict__ W16,
                                                  f16* __restrict__ abuf,
                                                  unsigned* __restrict__ bar) {
    int gtid = blockIdx.x * 256 + threadIdx.x;  // 0..262143
    int i = gtid * 4;
    float4 v = *(const float4*)(W + i);
    f16x4 h;
    h[0] = (f16)v.x; h[1] = (f16)v.y; h[2] = (f16)v.z; h[3] = (f16)v.w;
    *(f16x4*)(W16 + i) = h;
    // zero parity-0 state buffers: group g dwords [g*16384, g*16384+8192)
    if (gtid < 32768) {
        int g = gtid >> 13, off = gtid & 8191;
        ((unsigned*)abuf)[g * 16384 + off] = 0u;
    }
    if (gtid < 4) bar[gtid * 64] = 0u;
}

// ---------------- K1: xproj = X @ W_ax^T + b_a -> d_out[s][b][h] -------------
// fp16 split-2 on X, single f16 W_ax. 64x64 tile, 4 waves 2x2. (unchanged, validated)
__global__ __launch_bounds__(256) void k1_xproj(const float* __restrict__ X,
                                                const float* __restrict__ Wax,
                                                const float* __restrict__ ba,
                                                float* __restrict__ out) {
    __shared__ __align__(16) f16 Xhi[64][40];
    __shared__ __align__(16) f16 Xlo[64][40];
    __shared__ __align__(16) f16 Wh[64][40];
    const int tid  = threadIdx.x;
    const int lane = tid & 63;
    const int wave = tid >> 6;
    const int vm = wave >> 1, vn = wave & 1;
    const int m0 = blockIdx.x * 64;   // m = b*512 + s
    const int n0 = blockIdx.y * 64;   // n = h
    const int q = lane >> 4, c = lane & 15;
    const int srow = tid >> 2, scol = (tid & 3) * 8;

    floatx4 acc[2][2] = {};

    for (int kc = 0; kc < EMB; kc += 32) {
        const float* xp = X + (size_t)(m0 + srow) * EMB + kc + scol;
        float4 x0 = *(const float4*)xp;
        float4 x1 = *(const float4*)(xp + 4);
        float xv[8] = {x0.x, x0.y, x0.z, x0.w, x1.x, x1.y, x1.z, x1.w};
        half8 xh, xl;
#pragma unroll
        for (int j = 0; j < 8; j++) {
            f16 h = (f16)xv[j];
            xh[j] = h;
            xl[j] = (f16)(xv[j] - (float)h);
        }
        *(half8*)&Xhi[srow][scol] = xh;
        *(half8*)&Xlo[srow][scol] = xl;
        const float* wp = Wax + (size_t)(n0 + srow) * EMB + kc + scol;
        float4 w0 = *(const float4*)wp;
        float4 w1 = *(const float4*)(wp + 4);
        float wv[8] = {w0.x, w0.y, w0.z, w0.w, w1.x, w1.y, w1.z, w1.w};
        half8 wh8;
#pragma unroll
        for (int j = 0; j < 8; j++) wh8[j] = (f16)wv[j];
        *(half8*)&Wh[srow][scol] = wh8;
        __syncthreads();

#pragma unroll
        for (int im = 0; im < 2; im++) {
            half8 ahi = *(const half8*)&Xhi[vm * 32 + im * 16 + c][q * 8];
            half8 alo = *(const half8*)&Xlo[vm * 32 + im * 16 + c][q * 8];
#pragma unroll
            for (int in = 0; in < 2; in++) {
                half8 bf = *(const half8*)&Wh[vn * 32 + in * 16 + c][q * 8];
                acc[im][in] = __builtin_amdgcn_mfma_f32_16x16x32_f16(ahi, bf, acc[im][in], 0, 0, 0);
                acc[im][in] = __builtin_amdgcn_mfma_f32_16x16x32_f16(alo, bf, acc[im][in], 0, 0, 0);
            }
        }
        __syncthreads();
    }
#pragma unroll
    for (int im = 0; im < 2; im++) {
#pragma unroll
        for (int in = 0; in < 2; in++) {
            int n = n0 + vn * 32 + in * 16 + c;
            float bias = ba[n];
#pragma unroll
            for (int r = 0; r < 4; r++) {
                int m = m0 + vm * 32 + im * 16 + q * 4 + r;
                int b = m >> 9, s = m & 511;
                out[(size_t)(s * BATCH + b) * HID + n] = acc[im][in][r] + bias;
            }
        }
    }
}

// ---------------- K2: scan with per-b-group hand barrier ---------------------
// 32 WGs x 512 thr. group = blockIdx/8 (b0=group*16). wave-in-group = (blockIdx%8)*8+wave,
// j0 = wig*16. W_aa rows held in registers (32 x half8 = 128 VGPR). State single f16,
// double-buffered in ws; staged to LDS per WG per step. Barrier: monotonic counter,
// 8 arrivals/group/step, tid0 spins with relaxed agent loads + s_sleep.
__global__ __launch_bounds__(512, 1) void k2_scan(const f16* __restrict__ W16,
                                                  float* __restrict__ out,
                                                  f16* __restrict__ abuf,
                                                  unsigned* __restrict__ bar) {
    __shared__ __align__(16) f16 S[16][1032];  // +8 pad
    const int tid  = threadIdx.x;
    const int lane = tid & 63;
    const int wave = tid >> 6;                    // 0..7
    const int grp  = blockIdx.x >> 3;             // 0..3
    const int wig  = ((blockIdx.x & 7) << 3) + wave;  // 0..63
    const int j0   = wig << 4;
    const int b0   = grp << 4;
    const int q = lane >> 4, c = lane & 15;

    // A-operand (W) fragments, resident in VGPRs for the whole scan:
    // lane holds W[j0+c][t*32 + q*8 .. +7] for t=0..31
    half8 w[32];
    {
        const f16* Wrow = W16 + (size_t)(j0 + c) * HID + q * 8;
#pragma unroll
        for (int t = 0; t < 32; t++) w[t] = *(const half8*)(Wrow + t * 32);
    }
    unsigned* cnt = bar + grp * 64;
    f16* const buf0 = abuf + (size_t)grp * 32768;
    f16* const buf1 = buf0 + 16384;

    for (int s = 0; s < SEQ; s++) {
        const f16* src = (s & 1) ? buf1 : buf0;
        f16* dst       = (s & 1) ? buf0 : buf1;
        // prefetch xp (independent of barrier; hides HBM latency under spin)
        const int b = b0 + c;
        size_t obase = ((size_t)s * BATCH + b) * HID + j0 + (q << 2);
        float4 xp = *(const float4*)(out + obase);
        // ---- barrier wait: state for step s ready when cnt >= 8*s ----
        if (tid == 0) {
            unsigned tgt = (unsigned)(GWG * s);
            while (__hip_atomic_load(cnt, __ATOMIC_RELAXED, __HIP_MEMORY_SCOPE_AGENT) < tgt)
                __builtin_amdgcn_s_sleep(1);
        }
        __syncthreads();
        __threadfence();  // acquire: see other XCDs' state writes
        // ---- stage state (16384 f16) into LDS: 512 thr x 8 halfs x 4 iters ----
#pragma unroll
        for (int it = 0; it < 4; it++) {
            int idx = (it * 512 + tid) * 8;
            half8 v8 = *(const half8*)(src + idx);
            *(half8*)&S[idx >> 10][idx & 1023] = v8;
        }
        __syncthreads();
        // ---- K-loop: 32 chunks, W from regs, B-frag from LDS ----
        floatx4 acc = {0.f, 0.f, 0.f, 0.f};
#pragma unroll
        for (int t = 0; t < 32; t++) {
            half8 bfrag = *(const half8*)&S[c][t * 32 + q * 8];
            acc = __builtin_amdgcn_mfma_f32_16x16x32_f16(w[t], bfrag, acc, 0, 0, 0);
        }
        // ---- epilogue: lane l reg r -> j = j0+q*4+r, b = b0+c ----
        float4 v;
        v.x = tanhf(xp.x + acc[0]);
        v.y = tanhf(xp.y + acc[1]);
        v.z = tanhf(xp.z + acc[2]);
        v.w = tanhf(xp.w + acc[3]);
        *(float4*)(out + obase) = v;
        f16x4 hv;
        hv[0] = (f16)v.x; hv[1] = (f16)v.y; hv[2] = (f16)v.z; hv[3] = (f16)v.w;
        *(f16x4*)(dst + c * 1024 + j0 + (q << 2)) = hv;
        if (s == SEQ - 1)
            *(float4*)(out + (size_t)SEQ * BATCH * HID + (size_t)b * HID + j0 + (q << 2)) = v;
        // ---- barrier arrive ----
        __threadfence();  // release: state stores visible device-wide
        __syncthreads();  // whole WG fenced before the add
        if (tid == 0)
            __hip_atomic_fetch_add(cnt, 1u, __ATOMIC_RELAXED, __HIP_MEMORY_SCOPE_AGENT);
    }
}

extern "C" void kernel_launch(void* const* d_in, const int* in_sizes, int n_in,
                              void* d_out, int out_size, void* d_ws, size_t ws_size,
                              hipStream_t stream) {
    const float* X   = (const float*)d_in[0];
    const float* Wax = (const float*)d_in[1];
    const float* Waa = (const float*)d_in[2];
    const float* ba  = (const float*)d_in[3];
    float* out = (float*)d_out;

    f16* abuf = (f16*)d_ws;
    f16* W16  = abuf + ABUF_HALFS;
    unsigned* bar = (unsigned*)((char*)d_ws + BAR_OFF);

    k0_cvt_waa<<<dim3(HID * HID / 1024), dim3(256), 0, stream>>>(Waa, W16, abuf, bar);
    k1_xproj<<<dim3((BATCH * SEQ) / 64, HID / 64), dim3(256), 0, stream>>>(X, Wax, ba, out);

    void* args[] = {(void*)&W16, (void*)&out, (void*)&abuf, (void*)&bar};
    hipLaunchCooperativeKernel((void*)k2_scan, dim3(32), dim3(512), args, 0, stream);
}

// Round 3
// 2894.691 us; speedup vs baseline: 3.9053x; 2.3655x over previous
//
#include <hip/hip_runtime.h>
#include <hip/hip_fp16.h>
#include <hip/hip_cooperative_groups.h>

typedef _Float16 f16;
typedef _Float16 half8 __attribute__((ext_vector_type(8)));
typedef _Float16 f16x4 __attribute__((ext_vector_type(4)));
typedef float floatx4 __attribute__((ext_vector_type(4)));
typedef unsigned long long u64;

#define BATCH 64
#define SEQ 512
#define EMB 512
#define HID 1024
#define GWG 8  // workgroups per b-group (512 threads each -> 64 waves/group)

// ws layout (bytes):
//   [0, 262144)          abuf: 4 groups x 2 parity x 16384 f16 (state, single f16 plane)
//   [262144, 2359296)    W16: W_aa as f16, 1M elements
//   [2359296, +1KB)      barrier counters, 4 x u32 at 256B stride
#define ABUF_HALFS 131072
#define BAR_OFF 2359296

// ---------------- K0: convert W_aa fp32->f16; zero state buf0 + counters -----
__global__ __launch_bounds__(256) void k0_cvt_waa(const float* __restrict__ W,
                                                  f16* __restrict__ W16,
                                                  f16* __restrict__ abuf,
                                                  unsigned* __restrict__ bar) {
    int gtid = blockIdx.x * 256 + threadIdx.x;  // 0..262143
    int i = gtid * 4;
    float4 v = *(const float4*)(W + i);
    f16x4 h;
    h[0] = (f16)v.x; h[1] = (f16)v.y; h[2] = (f16)v.z; h[3] = (f16)v.w;
    *(f16x4*)(W16 + i) = h;
    // zero parity-0 state buffers: group g dwords [g*16384, g*16384+8192)
    if (gtid < 32768) {
        int g = gtid >> 13, off = gtid & 8191;
        ((unsigned*)abuf)[g * 16384 + off] = 0u;
    }
    if (gtid < 4) bar[gtid * 64] = 0u;
}

// ---------------- K1: xproj = X @ W_ax^T + b_a -> d_out[s][b][h] -------------
// fp16 split-2 on X, single f16 W_ax. 64x64 tile, 4 waves 2x2. (validated R1)
__global__ __launch_bounds__(256) void k1_xproj(const float* __restrict__ X,
                                                const float* __restrict__ Wax,
                                                const float* __restrict__ ba,
                                                float* __restrict__ out) {
    __shared__ __align__(16) f16 Xhi[64][40];
    __shared__ __align__(16) f16 Xlo[64][40];
    __shared__ __align__(16) f16 Wh[64][40];
    const int tid  = threadIdx.x;
    const int lane = tid & 63;
    const int wave = tid >> 6;
    const int vm = wave >> 1, vn = wave & 1;
    const int m0 = blockIdx.x * 64;   // m = b*512 + s
    const int n0 = blockIdx.y * 64;   // n = h
    const int q = lane >> 4, c = lane & 15;
    const int srow = tid >> 2, scol = (tid & 3) * 8;

    floatx4 acc[2][2] = {};

    for (int kc = 0; kc < EMB; kc += 32) {
        const float* xp = X + (size_t)(m0 + srow) * EMB + kc + scol;
        float4 x0 = *(const float4*)xp;
        float4 x1 = *(const float4*)(xp + 4);
        float xv[8] = {x0.x, x0.y, x0.z, x0.w, x1.x, x1.y, x1.z, x1.w};
        half8 xh, xl;
#pragma unroll
        for (int j = 0; j < 8; j++) {
            f16 h = (f16)xv[j];
            xh[j] = h;
            xl[j] = (f16)(xv[j] - (float)h);
        }
        *(half8*)&Xhi[srow][scol] = xh;
        *(half8*)&Xlo[srow][scol] = xl;
        const float* wp = Wax + (size_t)(n0 + srow) * EMB + kc + scol;
        float4 w0 = *(const float4*)wp;
        float4 w1 = *(const float4*)(wp + 4);
        float wv[8] = {w0.x, w0.y, w0.z, w0.w, w1.x, w1.y, w1.z, w1.w};
        half8 wh8;
#pragma unroll
        for (int j = 0; j < 8; j++) wh8[j] = (f16)wv[j];
        *(half8*)&Wh[srow][scol] = wh8;
        __syncthreads();

#pragma unroll
        for (int im = 0; im < 2; im++) {
            half8 ahi = *(const half8*)&Xhi[vm * 32 + im * 16 + c][q * 8];
            half8 alo = *(const half8*)&Xlo[vm * 32 + im * 16 + c][q * 8];
#pragma unroll
            for (int in = 0; in < 2; in++) {
                half8 bf = *(const half8*)&Wh[vn * 32 + in * 16 + c][q * 8];
                acc[im][in] = __builtin_amdgcn_mfma_f32_16x16x32_f16(ahi, bf, acc[im][in], 0, 0, 0);
                acc[im][in] = __builtin_amdgcn_mfma_f32_16x16x32_f16(alo, bf, acc[im][in], 0, 0, 0);
            }
        }
        __syncthreads();
    }
#pragma unroll
    for (int im = 0; im < 2; im++) {
#pragma unroll
        for (int in = 0; in < 2; in++) {
            int n = n0 + vn * 32 + in * 16 + c;
            float bias = ba[n];
#pragma unroll
            for (int r = 0; r < 4; r++) {
                int m = m0 + vm * 32 + im * 16 + q * 4 + r;
                int b = m >> 9, s = m & 511;
                out[(size_t)(s * BATCH + b) * HID + n] = acc[im][in][r] + bias;
            }
        }
    }
}

// ---------------- K2: scan, fence-free state exchange ------------------------
// 32 WGs x 512 thr. group = blockIdx/8 (b0=group*16), wig = (blockIdx%8)*8+wave,
// j0 = wig*16. W_aa rows in registers (32 x half8). State single f16, double-
// buffered; exchanged via RELAXED AGENT-scope 8B atomics (L1/L2-bypassing, no
// cache-wide fences). Arrival: s_waitcnt vmcnt(0) -> syncthreads -> atomicAdd.
__global__ __launch_bounds__(512, 1) void k2_scan(const f16* __restrict__ W16,
                                                  float* __restrict__ out,
                                                  f16* __restrict__ abuf,
                                                  unsigned* __restrict__ bar) {
    __shared__ __align__(16) f16 S[16][1032];  // +8 pad
    const int tid  = threadIdx.x;
    const int lane = tid & 63;
    const int wave = tid >> 6;                        // 0..7
    const int grp  = blockIdx.x >> 3;                 // 0..3
    const int wig  = ((blockIdx.x & 7) << 3) + wave;  // 0..63
    const int j0   = wig << 4;
    const int b0   = grp << 4;
    const int q = lane >> 4, c = lane & 15;

    // A-operand (W) fragments resident for the whole scan:
    // lane holds W[j0+c][t*32 + q*8 .. +7] for t=0..31
    half8 w[32];
    {
        const f16* Wrow = W16 + (size_t)(j0 + c) * HID + q * 8;
#pragma unroll
        for (int t = 0; t < 32; t++) w[t] = *(const half8*)(Wrow + t * 32);
    }
    unsigned* cnt = bar + grp * 64;
    f16* const buf0 = abuf + (size_t)grp * 32768;
    f16* const buf1 = buf0 + 16384;

    for (int s = 0; s < SEQ; s++) {
        const f16* src = (s & 1) ? buf1 : buf0;
        f16* dst       = (s & 1) ? buf0 : buf1;
        // prefetch xp (independent of barrier; hides HBM latency under spin)
        const int b = b0 + c;
        size_t obase = ((size_t)s * BATCH + b) * HID + j0 + (q << 2);
        float4 xp = *(const float4*)(out + obase);
        // ---- wait: state for step s ready when cnt >= 8*s ----
        if (tid == 0) {
            unsigned tgt = (unsigned)(GWG * s);
            while (__hip_atomic_load(cnt, __ATOMIC_RELAXED, __HIP_MEMORY_SCOPE_AGENT) < tgt) {}
        }
        __syncthreads();
        // ---- stage state (16384 f16 = 32 KB) into LDS via coherent 8B loads ----
#pragma unroll
        for (int it = 0; it < 8; it++) {
            int idx = (it * 512 + tid) * 4;  // half index, 8B chunks
            u64 bits = __hip_atomic_load((const u64*)(src + idx),
                                         __ATOMIC_RELAXED, __HIP_MEMORY_SCOPE_AGENT);
            *(u64*)&S[idx >> 10][idx & 1023] = bits;
        }
        __syncthreads();
        // ---- K-loop: 32 chunks, W from regs, B-frag from LDS ----
        floatx4 acc = {0.f, 0.f, 0.f, 0.f};
#pragma unroll
        for (int t = 0; t < 32; t++) {
            half8 bfrag = *(const half8*)&S[c][t * 32 + q * 8];
            acc = __builtin_amdgcn_mfma_f32_16x16x32_f16(w[t], bfrag, acc, 0, 0, 0);
        }
        // ---- epilogue: lane l reg r -> j = j0+q*4+r, b = b0+c ----
        float4 v;
        v.x = tanhf(xp.x + acc[0]);
        v.y = tanhf(xp.y + acc[1]);
        v.z = tanhf(xp.z + acc[2]);
        v.w = tanhf(xp.w + acc[3]);
        *(float4*)(out + obase) = v;
        union { f16x4 h; u64 u; } cv;
        cv.h[0] = (f16)v.x; cv.h[1] = (f16)v.y; cv.h[2] = (f16)v.z; cv.h[3] = (f16)v.w;
        __hip_atomic_store((u64*)(dst + c * 1024 + j0 + (q << 2)), cv.u,
                           __ATOMIC_RELAXED, __HIP_MEMORY_SCOPE_AGENT);
        if (s == SEQ - 1)
            *(float4*)(out + (size_t)SEQ * BATCH * HID + (size_t)b * HID + j0 + (q << 2)) = v;
        // ---- arrive: drain own stores, whole-WG rendezvous, then count up ----
        asm volatile("s_waitcnt vmcnt(0)" ::: "memory");
        __syncthreads();
        if (tid == 0)
            __hip_atomic_fetch_add(cnt, 1u, __ATOMIC_RELAXED, __HIP_MEMORY_SCOPE_AGENT);
    }
}

extern "C" void kernel_launch(void* const* d_in, const int* in_sizes, int n_in,
                              void* d_out, int out_size, void* d_ws, size_t ws_size,
                              hipStream_t stream) {
    const float* X   = (const float*)d_in[0];
    const float* Wax = (const float*)d_in[1];
    const float* Waa = (const float*)d_in[2];
    const float* ba  = (const float*)d_in[3];
    float* out = (float*)d_out;

    f16* abuf = (f16*)d_ws;
    f16* W16  = abuf + ABUF_HALFS;
    unsigned* bar = (unsigned*)((char*)d_ws + BAR_OFF);

    k0_cvt_waa<<<dim3(HID * HID / 1024), dim3(256), 0, stream>>>(Waa, W16, abuf, bar);
    k1_xproj<<<dim3((BATCH * SEQ) / 64, HID / 64), dim3(256), 0, stream>>>(X, Wax, ba, out);

    void* args[] = {(void*)&W16, (void*)&out, (void*)&abuf, (void*)&bar};
    hipLaunchCooperativeKernel((void*)k2_scan, dim3(32), dim3(512), args, 0, stream);
}